// Round 11
// baseline (468.315 us; speedup 1.0000x reference)
//
#include <hip/hip_runtime.h>

// Problem constants: B=4, T=2048, C=2048, N_HEAD=16, N_KV_HEAD=8, HEAD_DIM=128
#define SCALE 0.08838834764831845f  // 1/sqrt(128)

typedef unsigned short bfu;  // bf16 bits
typedef __attribute__((ext_vector_type(8))) short bf16x8;
typedef __attribute__((ext_vector_type(4))) float f32x4;
typedef __attribute__((ext_vector_type(16))) float f32x16;

__device__ __forceinline__ unsigned short f2bf(float f) {
  unsigned int u = __float_as_uint(f);
  u += 0x7FFFu + ((u >> 16) & 1u);  // RNE
  return (unsigned short)(u >> 16);
}
__device__ __forceinline__ float bf2f(unsigned short h) {
  return __uint_as_float(((unsigned int)h) << 16);
}
// HW packed f32->bf16 RNE convert (bit-identical to f2bf pair, 1 instr)
__device__ __forceinline__ unsigned int cvtpk(float a, float b) {
  unsigned int r;
  asm("v_cvt_pk_bf16_f32 %0, %1, %2" : "=v"(r) : "v"(a), "v"(b));
  return r;
}
// v_permlane32_swap_b32 a,b: a' = {A_lo, B_lo}, b' = {A_hi, B_hi}
__device__ __forceinline__ void pl32swap(unsigned int& a, unsigned int& b) {
  asm volatile("v_permlane32_swap_b32 %0, %1" : "+v"(a), "+v"(b));
}
__device__ __forceinline__ void async16(const void* g, void* l) {
  __builtin_amdgcn_global_load_lds(
      (const __attribute__((address_space(1))) unsigned int*)g,
      (__attribute__((address_space(3))) unsigned int*)l, 16, 0, 0);
}
// raw barrier (no vmcnt(0) drain!) pinned against compiler reordering
__device__ __forceinline__ void barrier_sb() {
  __builtin_amdgcn_sched_barrier(0);
  __builtin_amdgcn_s_barrier();
  __builtin_amdgcn_sched_barrier(0);
}
__device__ __forceinline__ void wait0_bar() {
  __builtin_amdgcn_sched_barrier(0);
  asm volatile("s_waitcnt vmcnt(0)" ::: "memory");
  __builtin_amdgcn_s_barrier();
  __builtin_amdgcn_sched_barrier(0);
}

// ---------------- fp32 -> bf16 convert ----------------
__global__ __launch_bounds__(256) void cvt_bf16(const float* __restrict__ src,
                                                bfu* __restrict__ dst, int n4) {
  int i = blockIdx.x * 256 + threadIdx.x;
  if (i >= n4) return;
  float4 v = ((const float4*)src)[i];
  ushort4 o;
  o.x = f2bf(v.x); o.y = f2bf(v.y); o.z = f2bf(v.z); o.w = f2bf(v.w);
  ((ushort4*)dst)[i] = o;
}

// ---------------- RoPE cos/sin table [2048][64] float2 -------------------
__global__ __launch_bounds__(256) void rope_table(float2* __restrict__ tab) {
  int idx = blockIdx.x * 256 + threadIdx.x;  // 2048*64
  int t = idx >> 6, f = idx & 63;
  const float nl = -0.14391156463f;  // -ln(10000)/64
  float th = (float)t * expf((float)f * nl);
  tab[idx] = make_float2(cosf(th), sinf(th));
}

__device__ __forceinline__ void storeC(float* p, float v) { *p = v; }
__device__ __forceinline__ void storeC(bfu* p, float v) { *p = f2bf(v); }

// ---------------- GEMM 256x256 tile, BK=64 (QKV, fused epilogue) ---------
// r8-verified 2-barrier K-loop + r10-verified 2D XCD map.
template <typename OutT, bool FUSE>
__global__ __launch_bounds__(512, 2) void gemm256(
    const bfu* __restrict__ A, const bfu* __restrict__ B,
    OutT* __restrict__ C, const float2* __restrict__ ropeTab,
    bfu* __restrict__ qTo, bfu* __restrict__ kTo, bfu* __restrict__ vTo,
    int M, int N, int K) {
  __shared__ __align__(16) char smem[131072];
  const int tid = threadIdx.x;
  const int w = tid >> 6, l = tid & 63;
  const int lr = l & 15, lg = l >> 4;
  const int wr = w >> 2, wc = w & 3;

  // XCD = flat%8. Per-XCD 2D region: RM x 4 tiles, n-fastest.
  const int nm = gridDim.x, nn = gridDim.y;
  const int flat = blockIdx.y * nm + blockIdx.x;
  const int xcd = flat & 7, j = flat >> 3;
  const int RM = (nm * nn) >> 5;
  const int nregm = nm / RM;
  const int m0 = ((xcd % nregm) * RM + (j >> 2)) * 256;
  const int n0 = ((xcd / nregm) * 4 + (j & 3)) * 256;

  const int sr = l >> 3;
  const int sc = (l & 7) ^ sr;
  auto stageHalf = [&](const bfu* G, int grow0, int kcol, char* lds) {
#pragma unroll
    for (int jj = 0; jj < 2; jj++) {
      int row = (jj * 8 + w) * 8 + sr;
      async16(G + (size_t)(grow0 + row) * K + kcol + sc * 8,
              lds + (jj * 8 + w) * 1024 + l * 16);
    }
  };

  f32x4 acc[8][4];
#pragma unroll
  for (int i = 0; i < 8; i++)
#pragma unroll
    for (int jj = 0; jj < 4; jj++) acc[i][jj] = (f32x4){0.f, 0.f, 0.f, 0.f};

  stageHalf(A, m0, 0, smem);
  stageHalf(A, m0 + 128, 0, smem + 16384);
  stageHalf(B, n0, 0, smem + 65536);
  stageHalf(B, n0 + 128, 0, smem + 65536 + 16384);

  const int KT = K >> 6;
  const int swiz = (lr & 7) << 4;
  const int cbase = (wc >> 1) * 128 + (wc & 1) * 32;
#pragma unroll 1
  for (int t = 0; t < KT; t++) {
    const int bt = t & 1;
    const char* Ah = smem + bt * 32768 + wr * 16384;
    const char* Bt = smem + 65536 + bt * 32768;
    char* An = smem + (bt ^ 1) * 32768;
    char* Bn = smem + 65536 + (bt ^ 1) * 32768;
    const bool pfch = (t + 1 < KT);
    const int kn = (t + 1) << 6;

    if (pfch) {
      stageHalf(A, m0, kn, An);
      asm volatile("s_waitcnt vmcnt(2)" ::: "memory");
    } else {
      asm volatile("s_waitcnt vmcnt(0)" ::: "memory");
    }
    barrier_sb();

    bf16x8 bfr[4][2];
#pragma unroll
    for (int n = 0; n < 4; n++) {
      const char* rowp =
          Bt + (cbase + (n & 1) * 16 + (n >> 1) * 64 + lr) * 128;
#pragma unroll
      for (int s = 0; s < 2; s++)
        bfr[n][s] = *(const bf16x8*)(rowp + ((((s << 2) + lg) << 4) ^ swiz));
    }

#pragma unroll
    for (int p = 0; p < 4; p++) {
      bf16x8 af[2][2];
#pragma unroll
      for (int m2 = 0; m2 < 2; m2++) {
        const char* rowp = Ah + ((p * 2 + m2) * 16 + lr) * 128;
#pragma unroll
        for (int s = 0; s < 2; s++)
          af[m2][s] = *(const bf16x8*)(rowp + ((((s << 2) + lg) << 4) ^ swiz));
      }
      if (pfch) {
        if (p == 1) stageHalf(A, m0 + 128, kn, An + 16384);
        if (p == 2) stageHalf(B, n0, kn, Bn);
        if (p == 3) stageHalf(B, n0 + 128, kn, Bn + 16384);
      }
      __builtin_amdgcn_s_setprio(1);
#pragma unroll
      for (int m2 = 0; m2 < 2; m2++)
#pragma unroll
        for (int n = 0; n < 4; n++)
#pragma unroll
          for (int s = 0; s < 2; s++)
            acc[p * 2 + m2][n] = __builtin_amdgcn_mfma_f32_16x16x32_bf16(
                af[m2][s], bfr[n][s], acc[p * 2 + m2][n], 0, 0, 0);
      __builtin_amdgcn_s_setprio(0);
    }
    barrier_sb();
  }

  if constexpr (!FUSE) {
#pragma unroll
    for (int i = 0; i < 8; i++)
#pragma unroll
      for (int jj = 0; jj < 4; jj++)
#pragma unroll
        for (int r = 0; r < 4; r++) {
          int gm = m0 + wr * 128 + i * 16 + lg * 4 + r;
          int gn = n0 + cbase + (jj & 1) * 16 + (jj >> 1) * 64 + lr;
          storeC(&C[(size_t)gm * N + gn], acc[i][jj][r]);
        }
  } else {
    const int head = (n0 >> 7) + (wc >> 1);
    if (head < 24) {
#pragma unroll
      for (int i = 0; i < 8; i++)
#pragma unroll
        for (int r = 0; r < 4; r++) {
          int gm = m0 + wr * 128 + i * 16 + lg * 4 + r;
          int tt = gm & 2047, bb = gm >> 11;
          bfu* rowp = (head < 16)
                          ? qTo + (((size_t)((bb * 16 + head) * 2048 + tt)) << 7)
                          : kTo + (((size_t)((bb * 8 + head - 16) * 2048 + tt)) << 7);
          const float2* trow = ropeTab + tt * 64;
#pragma unroll
          for (int n = 0; n < 2; n++) {
            int d = (wc & 1) * 32 + n * 16 + lr;  // 0..63
            int i1 = d >> 1;
            float2 cs1 = trow[i1];
            float2 cs2 = trow[i1 + 32];
            float x1 = acc[i][n][r], x2 = acc[i][n + 2][r];
            rowp[d] = f2bf(x1 * cs1.x - x2 * cs1.y);
            rowp[d + 64] = f2bf(x2 * cs2.x + x1 * cs2.y);
          }
        }
    } else {
      const int kh = head - 24;
#pragma unroll
      for (int i = 0; i < 8; i++) {
        int gm0 = m0 + wr * 128 + i * 16 + lg * 4;
        int t0 = gm0 & 2047, bb = gm0 >> 11;
#pragma unroll
        for (int n = 0; n < 4; n++) {
          int d = (wc & 1) * 32 + (n & 1) * 16 + (n >> 1) * 64 + lr;
          bfu* p = vTo + (((size_t)((bb * 8 + kh) * 128 + d)) << 11) + t0;
          ushort4 o;
          o.x = f2bf(acc[i][n][0]);
          o.y = f2bf(acc[i][n][1]);
          o.z = f2bf(acc[i][n][2]);
          o.w = f2bf(acc[i][n][3]);
          *(ushort4*)p = o;
        }
      }
    }
  }
}

// ---------------- GEMM 128x128 tile, BK=64 (projection) ------------------
// Same verified 2-barrier schedule + swizzle, quarter tile: LDS 64KB ->
// 2 blocks/CU resident (proj's 256-block grid at 256sq had 1/CU with all
// stage-wait gaps exposed). Grid 64x16 = 1024 blocks = 4/CU queued.
// 8 waves (2Mx4N), per-wave C = 64x32. K-order identical -> bit-identical.
__global__ __launch_bounds__(512, 2) void gemm128(const bfu* __restrict__ A,
                                                  const bfu* __restrict__ B,
                                                  float* __restrict__ C,
                                                  int M, int N, int K) {
  __shared__ __align__(16) char smem[65536];  // A: 2x16K @0, B: 2x16K @32768
  const int tid = threadIdx.x;
  const int w = tid >> 6, l = tid & 63;
  const int lr = l & 15, lg = l >> 4;
  const int wr = w >> 2, wc = w & 3;

  // 2D XCD map (nm=64, nn=16 -> RM=32, nregm=2; bijective)
  const int nm = gridDim.x, nn = gridDim.y;
  const int flat = blockIdx.y * nm + blockIdx.x;
  const int xcd = flat & 7, j = flat >> 3;
  const int RM = (nm * nn) >> 5;
  const int nregm = nm / RM;
  const int m0 = ((xcd % nregm) * RM + (j >> 2)) * 128;
  const int n0 = ((xcd / nregm) * 4 + (j & 3)) * 128;

  const int sr = l >> 3;
  const int sc = (l & 7) ^ sr;
  auto stageHalf = [&](const bfu* G, int grow0, int kcol, char* lds) {
#pragma unroll
    for (int jj = 0; jj < 2; jj++) {
      int row = (jj * 8 + w) * 8 + sr;  // 0..127
      async16(G + (size_t)(grow0 + row) * K + kcol + sc * 8,
              lds + (jj * 8 + w) * 1024 + l * 16);
    }
  };

  f32x4 acc[4][2];
#pragma unroll
  for (int i = 0; i < 4; i++)
#pragma unroll
    for (int n = 0; n < 2; n++) acc[i][n] = (f32x4){0.f, 0.f, 0.f, 0.f};

  stageHalf(A, m0, 0, smem);
  stageHalf(B, n0, 0, smem + 32768);

  const int KT = K >> 6;
  const int swiz = (lr & 7) << 4;
#pragma unroll 1
  for (int t = 0; t < KT; t++) {
    const int bt = t & 1;
    const char* Ah = smem + bt * 16384;
    const char* Bt = smem + 32768 + bt * 16384;
    char* An = smem + (bt ^ 1) * 16384;
    char* Bn = smem + 32768 + (bt ^ 1) * 16384;
    const bool pfch = (t + 1 < KT);
    const int kn = (t + 1) << 6;

    // boundary: stage A(t+1) [2 loads]; wait tile-t's 4 -> vmcnt(2)
    if (pfch) {
      stageHalf(A, m0, kn, An);
      asm volatile("s_waitcnt vmcnt(2)" ::: "memory");
    } else {
      asm volatile("s_waitcnt vmcnt(0)" ::: "memory");
    }
    barrier_sb();

    bf16x8 bfr[2][2];
#pragma unroll
    for (int n = 0; n < 2; n++) {
      const char* rowp = Bt + (wc * 32 + n * 16 + lr) * 128;
#pragma unroll
      for (int s = 0; s < 2; s++)
        bfr[n][s] = *(const bf16x8*)(rowp + ((((s << 2) + lg) << 4) ^ swiz));
    }

#pragma unroll
    for (int p = 0; p < 4; p++) {
      bf16x8 af[2];
      const char* rowp = Ah + (wr * 64 + p * 16 + lr) * 128;
#pragma unroll
      for (int s = 0; s < 2; s++)
        af[s] = *(const bf16x8*)(rowp + ((((s << 2) + lg) << 4) ^ swiz));
      if (p == 2 && pfch) stageHalf(B, n0, kn, Bn);  // B(t+1) [2 loads]
      __builtin_amdgcn_s_setprio(1);
#pragma unroll
      for (int n = 0; n < 2; n++)
#pragma unroll
        for (int s = 0; s < 2; s++)
          acc[p][n] = __builtin_amdgcn_mfma_f32_16x16x32_bf16(
              af[s], bfr[n][s], acc[p][n], 0, 0, 0);
      __builtin_amdgcn_s_setprio(0);
    }
    barrier_sb();
  }

#pragma unroll
  for (int i = 0; i < 4; i++)
#pragma unroll
    for (int n = 0; n < 2; n++)
#pragma unroll
      for (int r = 0; r < 4; r++) {
        int gm = m0 + wr * 64 + i * 16 + lg * 4 + r;
        int gn = n0 + wc * 32 + n * 16 + lr;
        C[(size_t)gm * N + gn] = acc[i][n][r];
      }
}

// ---------------- flash attention v7 (unchanged from round 8 — verified) -
__global__ __launch_bounds__(512, 2) void flash_attn7(const bfu* __restrict__ qT,
                                                      const bfu* __restrict__ kT,
                                                      const bfu* __restrict__ vT,
                                                      bfu* __restrict__ attn) {
  __shared__ __align__(16) char smem[65536];  // K: 2x16K @0, V: 2x16K @32768
  const int tid = threadIdx.x;
  const int w = tid >> 6, l = tid & 63;
  const int ln = l & 31, h2 = l >> 5;
  const int hsw = w >> 2, w4 = w & 3;
  const int idx = blockIdx.x;   // khb + 32*pg  (idx%8==kh -> XCD locality)
  const int khb = idx & 31;
  const int pg = idx >> 5;      // 0..7: tiles pg then 15-pg
  const int kh = khb & 7, b = khb >> 3;
  const int hh = kh * 2 + hsw;
  const int nkbA = 2 * pg + 2;
  const int NT = 34;            // uniform

  const bfu* Qh = qT + ((size_t)(b * 16 + hh) * 2048) * 128;
  const bfu* Kb = kT + ((size_t)(b * 8 + kh) * 2048) * 128;
  const bfu* Vb = vT + ((size_t)(b * 8 + kh) * 128) * 2048;

  auto stageK = [&](int buf, int t) {
    char* Kl = smem + buf * 16384;
    const bfu* src = Kb + (size_t)t * 64 * 128;
#pragma unroll
    for (int ii = 0; ii < 2; ii++) {
      int i = w * 2 + ii;                  // 0..15
      int row = i * 4 + (l >> 4);          // 0..63 key-in-tile
      int ck = (l & 15) ^ (row & 15);      // inverse swizzle on source
      async16(src + row * 128 + ck * 8, Kl + i * 1024 + l * 16);
    }
  };
  auto stageV = [&](int buf, int t) {
    char* Vl = smem + 32768 + buf * 16384;
    const bfu* src = Vb + t * 64;
#pragma unroll
    for (int jj = 0; jj < 2; jj++) {
      int j = w * 2 + jj;                  // 0..15
      int row = j * 8 + (l >> 3);          // 0..127 d
      int ck = (l & 7) ^ (row & 7);
      async16(src + (size_t)row * 2048 + ck * 8, Vl + j * 1024 + l * 16);
    }
  };

  int qrow0 = pg * 128 + w4 * 32;

  bf16x8 qf[8];
#pragma unroll
  for (int dt = 0; dt < 8; dt++)
    qf[dt] = *(const bf16x8*)(Qh + (size_t)(qrow0 + ln) * 128 + dt * 16 + h2 * 8);

  f32x16 O[4];  // O^T tiles over d (4 x 32)
#pragma unroll
  for (int mt = 0; mt < 4; mt++)
#pragma unroll
    for (int r = 0; r < 16; r++) O[mt][r] = 0.f;
  float li = 0.f;

  auto flush = [&]() {
    float ls = li + __shfl_xor(li, 32);
    float inv = 1.f / ls;
    bfu* orow = attn + ((size_t)(b * 2048 + qrow0 + ln)) * 2048 + hh * 128;
#pragma unroll
    for (int mt = 0; mt < 4; mt++)
#pragma unroll
      for (int g = 0; g < 4; g++) {
        unsigned int r0 = cvtpk(O[mt][g * 4 + 0] * inv, O[mt][g * 4 + 1] * inv);
        unsigned int r1 = cvtpk(O[mt][g * 4 + 2] * inv, O[mt][g * 4 + 3] * inv);
        uint2 o; o.x = r0; o.y = r1;
        *(uint2*)(orow + mt * 32 + g * 8 + h2 * 4) = o;
      }
  };

  stageK(0, 0);
  stageV(0, 0);

#pragma unroll 1
  for (int t = 0; t < NT; t++) {
    wait0_bar();
    if (t + 1 < NT) {
      const int kn = (t + 1 >= nkbA) ? (t + 1 - nkbA) : (t + 1);
      stageK((t + 1) & 1, kn);
      stageV((t + 1) & 1, kn);
    }

    if (t == nkbA) {  // tile A -> tile B transition
      flush();
      qrow0 = (15 - pg) * 128 + w4 * 32;
#pragma unroll
      for (int dt = 0; dt < 8; dt++)
        qf[dt] =
            *(const bf16x8*)(Qh + (size_t)(qrow0 + ln) * 128 + dt * 16 + h2 * 8);
#pragma unroll
      for (int mt = 0; mt < 4; mt++)
#pragma unroll
        for (int r = 0; r < 16; r++) O[mt][r] = 0.f;
      li = 0.f;
    }

    const int k0 = ((t >= nkbA) ? (t - nkbA) : t) * 64;
    const int myrow = qrow0 + ln;
    if (k0 <= qrow0 + 31) {
      const char* Kl = smem + (t & 1) * 16384;
      const char* Vl = smem + 32768 + (t & 1) * 16384;

      f32x16 S0, S1;  // S^T: m=key(32), n=row(32)
#pragma unroll
      for (int r = 0; r < 16; r++) { S0[r] = 0.f; S1[r] = 0.f; }
      const int swk = (ln & 15) << 4;
      __builtin_amdgcn_s_setprio(1);
#pragma unroll
      for (int dt = 0; dt < 8; dt++) {
        bf16x8 kf0 =
            *(const bf16x8*)(Kl + ln * 256 + ((dt * 32 + h2 * 16) ^ swk));
        bf16x8 kf1 = *(const bf16x8*)(Kl + (32 + ln) * 256 +
                                      ((dt * 32 + h2 * 16) ^ swk));
        S0 = __builtin_amdgcn_mfma_f32_32x32x16_bf16(kf0, qf[dt], S0, 0, 0, 0);
        S1 = __builtin_amdgcn_mfma_f32_32x32x16_bf16(kf1, qf[dt], S1, 0, 0, 0);
      }
      __builtin_amdgcn_s_setprio(0);

      const bool need_mask = (k0 + 63) > qrow0;
      bf16x8 pfr[4];
#pragma unroll
      for (int half = 0; half < 2; half++) {
        float p[16];
#pragma unroll
        for (int r = 0; r < 16; r++) {
          float s = half ? S1[r] : S0[r];
          float pv = __builtin_exp2f(fmaf(s, 0.12751743f, -17.312340f));
          if (need_mask) {
            int key = k0 + half * 32 + (r & 3) + 8 * (r >> 2) + 4 * h2;
            if (key > myrow) pv = 0.f;
          }
          p[r] = pv;
          li += pv;
        }
#pragma unroll
        for (int kt = 0; kt < 2; kt++) {
          const float* q = p + kt * 8;
          unsigned int a0 = cvtpk(q[0], q[1]);
          unsigned int a1 = cvtpk(q[2], q[3]);
          unsigned int b0 = cvtpk(q[4], q[5]);
          unsigned int b1 = cvtpk(q[6], q[7]);
          pl32swap(a0, b0);
          pl32swap(a1, b1);
          union { unsigned int u[4]; bf16x8 v; } c;
          c.u[0] = a0; c.u[1] = a1; c.u[2] = b0; c.u[3] = b1;
          pfr[half * 2 + kt] = c.v;
        }
      }

      const int swv = (ln & 7) << 4;
      __builtin_amdgcn_s_setprio(1);
#pragma unroll
      for (int mt = 0; mt < 4; mt++) {
        const char* vb = Vl + (mt * 32 + ln) * 128;
#pragma unroll
        for (int kt = 0; kt < 4; kt++) {
          bf16x8 vf = *(const bf16x8*)(vb + ((kt * 32 + h2 * 16) ^ swv));
          O[mt] = __builtin_amdgcn_mfma_f32_32x32x16_bf16(vf, pfr[kt], O[mt], 0, 0, 0);
        }
      }
      __builtin_amdgcn_s_setprio(0);
    }
  }

  flush();  // tile B epilogue
}

// ---------------- launch ----------------
extern "C" void kernel_launch(void* const* d_in, const int* in_sizes, int n_in,
                              void* d_out, int out_size, void* d_ws, size_t ws_size,
                              hipStream_t stream) {
  const float* x = (const float*)d_in[0];
  const float* Wq = (const float*)d_in[1];
  const float* Wk = (const float*)d_in[2];
  const float* Wv = (const float*)d_in[3];
  const float* Wo = (const float*)d_in[4];
  float* out = (float*)d_out;
  char* ws = (char*)d_ws;

  // workspace layout (bytes)
  bfu* xb     = (bfu*)(ws);               // 33,554,432  [8192 x 2048]
  bfu* Wqkv   = (bfu*)(ws + 33554432);    // 16,777,216  [4096 x 2048]
  bfu* Wob    = (bfu*)(ws + 50331648);    //  8,388,608  [2048 x 2048]
  float2* tab = (float2*)(ws + 58720256); //  1,048,576  [2048 x 64] cos/sin
  bfu* qT     = (bfu*)(ws + 125829120);   // 33,554,432  [B,16,T,128]
  bfu* kT     = (bfu*)(ws + 159383552);   // 16,777,216  [B,8,T,128]
  bfu* vT     = (bfu*)(ws + 176160768);   // 16,777,216  [B,8,128,T]
  bfu* attn = xb;                          // reuse xb region (alias-safe)

  cvt_bf16<<<16384, 256, 0, stream>>>(x, xb, 4194304);
  cvt_bf16<<<4096, 256, 0, stream>>>(Wq, Wqkv, 1048576);
  cvt_bf16<<<2048, 256, 0, stream>>>(Wk, Wqkv + (size_t)2048 * 2048, 524288);
  cvt_bf16<<<2048, 256, 0, stream>>>(Wv, Wqkv + (size_t)3072 * 2048, 524288);
  cvt_bf16<<<4096, 256, 0, stream>>>(Wo, Wob, 1048576);
  rope_table<<<512, 256, 0, stream>>>(tab);

  // fused QKV GEMM: writes qT/kT (RoPE'd) and vT (transposed) directly
  gemm256<bfu, true><<<dim3(32, 16), 512, 0, stream>>>(
      xb, Wqkv, (bfu*)nullptr, tab, qT, kT, vT, 8192, 4096, 2048);
  flash_attn7<<<256, 512, 0, stream>>>(qT, kT, vT, attn);
  gemm128<<<dim3(64, 16), 512, 0, stream>>>(attn, Wob, out, 8192, 2048, 2048);
}

// Round 12
// 450.809 us; speedup vs baseline: 1.0388x; 1.0388x over previous
//
#include <hip/hip_runtime.h>

// Problem constants: B=4, T=2048, C=2048, N_HEAD=16, N_KV_HEAD=8, HEAD_DIM=128
#define SCALE 0.08838834764831845f  // 1/sqrt(128)

typedef unsigned short bfu;  // bf16 bits
typedef __attribute__((ext_vector_type(8))) short bf16x8;
typedef __attribute__((ext_vector_type(4))) float f32x4;
typedef __attribute__((ext_vector_type(16))) float f32x16;

__device__ __forceinline__ unsigned short f2bf(float f) {
  unsigned int u = __float_as_uint(f);
  u += 0x7FFFu + ((u >> 16) & 1u);  // RNE
  return (unsigned short)(u >> 16);
}
__device__ __forceinline__ float bf2f(unsigned short h) {
  return __uint_as_float(((unsigned int)h) << 16);
}
// HW packed f32->bf16 RNE convert (bit-identical to f2bf pair, 1 instr)
__device__ __forceinline__ unsigned int cvtpk(float a, float b) {
  unsigned int r;
  asm("v_cvt_pk_bf16_f32 %0, %1, %2" : "=v"(r) : "v"(a), "v"(b));
  return r;
}
// v_permlane32_swap_b32 a,b: a' = {A_lo, B_lo}, b' = {A_hi, B_hi}
__device__ __forceinline__ void pl32swap(unsigned int& a, unsigned int& b) {
  asm volatile("v_permlane32_swap_b32 %0, %1" : "+v"(a), "+v"(b));
}
__device__ __forceinline__ void async16(const void* g, void* l) {
  __builtin_amdgcn_global_load_lds(
      (const __attribute__((address_space(1))) unsigned int*)g,
      (__attribute__((address_space(3))) unsigned int*)l, 16, 0, 0);
}
// raw barrier (no vmcnt(0) drain!) pinned against compiler reordering
__device__ __forceinline__ void barrier_sb() {
  __builtin_amdgcn_sched_barrier(0);
  __builtin_amdgcn_s_barrier();
  __builtin_amdgcn_sched_barrier(0);
}
__device__ __forceinline__ void wait0_bar() {
  __builtin_amdgcn_sched_barrier(0);
  asm volatile("s_waitcnt vmcnt(0)" ::: "memory");
  __builtin_amdgcn_s_barrier();
  __builtin_amdgcn_sched_barrier(0);
}

// ---------------- fp32 -> bf16 convert (x) ----------------
__global__ __launch_bounds__(256) void cvt_bf16(const float* __restrict__ src,
                                                bfu* __restrict__ dst, int n4) {
  int i = blockIdx.x * 256 + threadIdx.x;
  if (i >= n4) return;
  float4 v = ((const float4*)src)[i];
  ushort4 o;
  o.x = f2bf(v.x); o.y = f2bf(v.y); o.z = f2bf(v.z); o.w = f2bf(v.w);
  ((ushort4*)dst)[i] = o;
}

// ---------------- fp32 -> bf16 convert, all 4 weights in one launch ------
__global__ __launch_bounds__(256) void cvt_weights(
    const float* __restrict__ Wq, const float* __restrict__ Wk,
    const float* __restrict__ Wv, const float* __restrict__ Wo,
    bfu* __restrict__ Wqkv, bfu* __restrict__ Wob) {
  int i = blockIdx.x * 256 + threadIdx.x;  // 0..3145727 float4 groups
  const float* src; bfu* dst; int off;
  if (i < 1048576)      { src = Wq; dst = Wqkv;            off = i; }
  else if (i < 1572864) { src = Wk; dst = Wqkv + 4194304;  off = i - 1048576; }
  else if (i < 2097152) { src = Wv; dst = Wqkv + 6291456;  off = i - 1572864; }
  else                  { src = Wo; dst = Wob;             off = i - 2097152; }
  float4 v = ((const float4*)src)[off];
  ushort4 o;
  o.x = f2bf(v.x); o.y = f2bf(v.y); o.z = f2bf(v.z); o.w = f2bf(v.w);
  ((ushort4*)dst)[off] = o;
}

// ---------------- RoPE cos/sin table [2048][64] float2 -------------------
__global__ __launch_bounds__(256) void rope_table(float2* __restrict__ tab) {
  int idx = blockIdx.x * 256 + threadIdx.x;  // 2048*64
  int t = idx >> 6, f = idx & 63;
  const float nl = -0.14391156463f;  // -ln(10000)/64
  float th = (float)t * expf((float)f * nl);
  tab[idx] = make_float2(cosf(th), sinf(th));
}

__device__ __forceinline__ void storeC(float* p, float v) { *p = v; }
__device__ __forceinline__ void storeC(bfu* p, float v) { *p = f2bf(v); }

// ---------------- GEMM 256x256 tile, BK=64 (QKV, fused epilogue) ---------
// r8-verified 2-barrier K-loop + r10-verified 2D XCD map.
template <typename OutT, bool FUSE>
__global__ __launch_bounds__(512, 2) void gemm256(
    const bfu* __restrict__ A, const bfu* __restrict__ B,
    OutT* __restrict__ C, const float2* __restrict__ ropeTab,
    bfu* __restrict__ qTo, bfu* __restrict__ kTo, bfu* __restrict__ vTo,
    int M, int N, int K) {
  __shared__ __align__(16) char smem[131072];
  const int tid = threadIdx.x;
  const int w = tid >> 6, l = tid & 63;
  const int lr = l & 15, lg = l >> 4;
  const int wr = w >> 2, wc = w & 3;

  const int nm = gridDim.x, nn = gridDim.y;
  const int flat = blockIdx.y * nm + blockIdx.x;
  const int xcd = flat & 7, j = flat >> 3;
  const int RM = (nm * nn) >> 5;
  const int nregm = nm / RM;
  const int m0 = ((xcd % nregm) * RM + (j >> 2)) * 256;
  const int n0 = ((xcd / nregm) * 4 + (j & 3)) * 256;

  const int sr = l >> 3;
  const int sc = (l & 7) ^ sr;
  auto stageHalf = [&](const bfu* G, int grow0, int kcol, char* lds) {
#pragma unroll
    for (int jj = 0; jj < 2; jj++) {
      int row = (jj * 8 + w) * 8 + sr;
      async16(G + (size_t)(grow0 + row) * K + kcol + sc * 8,
              lds + (jj * 8 + w) * 1024 + l * 16);
    }
  };

  f32x4 acc[8][4];
#pragma unroll
  for (int i = 0; i < 8; i++)
#pragma unroll
    for (int jj = 0; jj < 4; jj++) acc[i][jj] = (f32x4){0.f, 0.f, 0.f, 0.f};

  stageHalf(A, m0, 0, smem);
  stageHalf(A, m0 + 128, 0, smem + 16384);
  stageHalf(B, n0, 0, smem + 65536);
  stageHalf(B, n0 + 128, 0, smem + 65536 + 16384);

  const int KT = K >> 6;
  const int swiz = (lr & 7) << 4;
  const int cbase = (wc >> 1) * 128 + (wc & 1) * 32;
#pragma unroll 1
  for (int t = 0; t < KT; t++) {
    const int bt = t & 1;
    const char* Ah = smem + bt * 32768 + wr * 16384;
    const char* Bt = smem + 65536 + bt * 32768;
    char* An = smem + (bt ^ 1) * 32768;
    char* Bn = smem + 65536 + (bt ^ 1) * 32768;
    const bool pfch = (t + 1 < KT);
    const int kn = (t + 1) << 6;

    if (pfch) {
      stageHalf(A, m0, kn, An);
      asm volatile("s_waitcnt vmcnt(2)" ::: "memory");
    } else {
      asm volatile("s_waitcnt vmcnt(0)" ::: "memory");
    }
    barrier_sb();

    bf16x8 bfr[4][2];
#pragma unroll
    for (int n = 0; n < 4; n++) {
      const char* rowp =
          Bt + (cbase + (n & 1) * 16 + (n >> 1) * 64 + lr) * 128;
#pragma unroll
      for (int s = 0; s < 2; s++)
        bfr[n][s] = *(const bf16x8*)(rowp + ((((s << 2) + lg) << 4) ^ swiz));
    }

#pragma unroll
    for (int p = 0; p < 4; p++) {
      bf16x8 af[2][2];
#pragma unroll
      for (int m2 = 0; m2 < 2; m2++) {
        const char* rowp = Ah + ((p * 2 + m2) * 16 + lr) * 128;
#pragma unroll
        for (int s = 0; s < 2; s++)
          af[m2][s] = *(const bf16x8*)(rowp + ((((s << 2) + lg) << 4) ^ swiz));
      }
      if (pfch) {
        if (p == 1) stageHalf(A, m0 + 128, kn, An + 16384);
        if (p == 2) stageHalf(B, n0, kn, Bn);
        if (p == 3) stageHalf(B, n0 + 128, kn, Bn + 16384);
      }
      __builtin_amdgcn_s_setprio(1);
#pragma unroll
      for (int m2 = 0; m2 < 2; m2++)
#pragma unroll
        for (int n = 0; n < 4; n++)
#pragma unroll
          for (int s = 0; s < 2; s++)
            acc[p * 2 + m2][n] = __builtin_amdgcn_mfma_f32_16x16x32_bf16(
                af[m2][s], bfr[n][s], acc[p * 2 + m2][n], 0, 0, 0);
      __builtin_amdgcn_s_setprio(0);
    }
    barrier_sb();
  }

  if constexpr (!FUSE) {
#pragma unroll
    for (int i = 0; i < 8; i++)
#pragma unroll
      for (int jj = 0; jj < 4; jj++)
#pragma unroll
        for (int r = 0; r < 4; r++) {
          int gm = m0 + wr * 128 + i * 16 + lg * 4 + r;
          int gn = n0 + cbase + (jj & 1) * 16 + (jj >> 1) * 64 + lr;
          storeC(&C[(size_t)gm * N + gn], acc[i][jj][r]);
        }
  } else {
    const int head = (n0 >> 7) + (wc >> 1);
    if (head < 24) {
#pragma unroll
      for (int i = 0; i < 8; i++)
#pragma unroll
        for (int r = 0; r < 4; r++) {
          int gm = m0 + wr * 128 + i * 16 + lg * 4 + r;
          int tt = gm & 2047, bb = gm >> 11;
          bfu* rowp = (head < 16)
                          ? qTo + (((size_t)((bb * 16 + head) * 2048 + tt)) << 7)
                          : kTo + (((size_t)((bb * 8 + head - 16) * 2048 + tt)) << 7);
          const float2* trow = ropeTab + tt * 64;
#pragma unroll
          for (int n = 0; n < 2; n++) {
            int d = (wc & 1) * 32 + n * 16 + lr;  // 0..63
            int i1 = d >> 1;
            float2 cs1 = trow[i1];
            float2 cs2 = trow[i1 + 32];
            float x1 = acc[i][n][r], x2 = acc[i][n + 2][r];
            rowp[d] = f2bf(x1 * cs1.x - x2 * cs1.y);
            rowp[d + 64] = f2bf(x2 * cs2.x + x1 * cs2.y);
          }
        }
    } else {
      const int kh = head - 24;
#pragma unroll
      for (int i = 0; i < 8; i++) {
        int gm0 = m0 + wr * 128 + i * 16 + lg * 4;
        int t0 = gm0 & 2047, bb = gm0 >> 11;
#pragma unroll
        for (int n = 0; n < 4; n++) {
          int d = (wc & 1) * 32 + (n & 1) * 16 + (n >> 1) * 64 + lr;
          bfu* p = vTo + (((size_t)((bb * 8 + kh) * 128 + d)) << 11) + t0;
          ushort4 o;
          o.x = f2bf(acc[i][n][0]);
          o.y = f2bf(acc[i][n][1]);
          o.z = f2bf(acc[i][n][2]);
          o.w = f2bf(acc[i][n][3]);
          *(ushort4*)p = o;
        }
      }
    }
  }
}

// ---------------- GEMM 128x128 tile, BK=64 (projection) ------------------
// (unchanged from round 11 — verified: proj dropped out of top-5)
__global__ __launch_bounds__(512, 2) void gemm128(const bfu* __restrict__ A,
                                                  const bfu* __restrict__ B,
                                                  float* __restrict__ C,
                                                  int M, int N, int K) {
  __shared__ __align__(16) char smem[65536];  // A: 2x16K @0, B: 2x16K @32768
  const int tid = threadIdx.x;
  const int w = tid >> 6, l = tid & 63;
  const int lr = l & 15, lg = l >> 4;
  const int wr = w >> 2, wc = w & 3;

  const int nm = gridDim.x, nn = gridDim.y;
  const int flat = blockIdx.y * nm + blockIdx.x;
  const int xcd = flat & 7, j = flat >> 3;
  const int RM = (nm * nn) >> 5;
  const int nregm = nm / RM;
  const int m0 = ((xcd % nregm) * RM + (j >> 2)) * 128;
  const int n0 = ((xcd / nregm) * 4 + (j & 3)) * 128;

  const int sr = l >> 3;
  const int sc = (l & 7) ^ sr;
  auto stageHalf = [&](const bfu* G, int grow0, int kcol, char* lds) {
#pragma unroll
    for (int jj = 0; jj < 2; jj++) {
      int row = (jj * 8 + w) * 8 + sr;  // 0..127
      async16(G + (size_t)(grow0 + row) * K + kcol + sc * 8,
              lds + (jj * 8 + w) * 1024 + l * 16);
    }
  };

  f32x4 acc[4][2];
#pragma unroll
  for (int i = 0; i < 4; i++)
#pragma unroll
    for (int n = 0; n < 2; n++) acc[i][n] = (f32x4){0.f, 0.f, 0.f, 0.f};

  stageHalf(A, m0, 0, smem);
  stageHalf(B, n0, 0, smem + 32768);

  const int KT = K >> 6;
  const int swiz = (lr & 7) << 4;
#pragma unroll 1
  for (int t = 0; t < KT; t++) {
    const int bt = t & 1;
    const char* Ah = smem + bt * 16384;
    const char* Bt = smem + 32768 + bt * 16384;
    char* An = smem + (bt ^ 1) * 16384;
    char* Bn = smem + 32768 + (bt ^ 1) * 16384;
    const bool pfch = (t + 1 < KT);
    const int kn = (t + 1) << 6;

    if (pfch) {
      stageHalf(A, m0, kn, An);
      asm volatile("s_waitcnt vmcnt(2)" ::: "memory");
    } else {
      asm volatile("s_waitcnt vmcnt(0)" ::: "memory");
    }
    barrier_sb();

    bf16x8 bfr[2][2];
#pragma unroll
    for (int n = 0; n < 2; n++) {
      const char* rowp = Bt + (wc * 32 + n * 16 + lr) * 128;
#pragma unroll
      for (int s = 0; s < 2; s++)
        bfr[n][s] = *(const bf16x8*)(rowp + ((((s << 2) + lg) << 4) ^ swiz));
    }

#pragma unroll
    for (int p = 0; p < 4; p++) {
      bf16x8 af[2];
      const char* rowp = Ah + (wr * 64 + p * 16 + lr) * 128;
#pragma unroll
      for (int s = 0; s < 2; s++)
        af[s] = *(const bf16x8*)(rowp + ((((s << 2) + lg) << 4) ^ swiz));
      if (p == 2 && pfch) stageHalf(B, n0, kn, Bn);  // B(t+1) [2 loads]
      __builtin_amdgcn_s_setprio(1);
#pragma unroll
      for (int n = 0; n < 2; n++)
#pragma unroll
        for (int s = 0; s < 2; s++)
          acc[p][n] = __builtin_amdgcn_mfma_f32_16x16x32_bf16(
              af[s], bfr[n][s], acc[p][n], 0, 0, 0);
      __builtin_amdgcn_s_setprio(0);
    }
    barrier_sb();
  }

#pragma unroll
  for (int i = 0; i < 4; i++)
#pragma unroll
    for (int n = 0; n < 2; n++)
#pragma unroll
      for (int r = 0; r < 4; r++) {
        int gm = m0 + wr * 64 + i * 16 + lg * 4 + r;
        int gn = n0 + wc * 32 + n * 16 + lr;
        C[(size_t)gm * N + gn] = acc[i][n][r];
      }
}

// ---------------- flash attention v8 — 2 blocks/CU, single q-tile --------
// 512 blocks = khb(32) x qt(16, descending; idx%8==kh -> XCD locality).
// Each block: ONE q-tile (128 rows), 8 waves (waves 0-3 head 2kh+0, 4-7
// head 2kh+1 — hs-merged staging as v7). LDS 64KB -> 2 blocks/CU resident:
// co-resident partner covers per-step barrier skew (r11 proj lesson).
// NT = 2qt+2 steps; long blocks dispatch first (backfill the imbalance).
// Per-step schedule, staging, swizzles, math: byte-identical to v7.
__global__ __launch_bounds__(512, 2) void flash_attn8(const bfu* __restrict__ qT,
                                                      const bfu* __restrict__ kT,
                                                      const bfu* __restrict__ vT,
                                                      bfu* __restrict__ attn) {
  __shared__ __align__(16) char smem[65536];  // K: 2x16K @0, V: 2x16K @32768
  const int tid = threadIdx.x;
  const int w = tid >> 6, l = tid & 63;
  const int ln = l & 31, h2 = l >> 5;
  const int hsw = w >> 2, w4 = w & 3;
  const int idx = blockIdx.x;   // khb + 32*(15-qt)
  const int khb = idx & 31;
  const int qt = 15 - (idx >> 5);  // descending: long blocks first
  const int kh = khb & 7, b = khb >> 3;
  const int hh = kh * 2 + hsw;
  const int NT = 2 * qt + 2;    // 64-key steps (block-uniform)
  const int qrow0 = qt * 128 + w4 * 32;
  const int myrow = qrow0 + ln;

  const bfu* Qh = qT + ((size_t)(b * 16 + hh) * 2048) * 128;
  const bfu* Kb = kT + ((size_t)(b * 8 + kh) * 2048) * 128;
  const bfu* Vb = vT + ((size_t)(b * 8 + kh) * 128) * 2048;

  auto stageK = [&](int buf, int t) {
    char* Kl = smem + buf * 16384;
    const bfu* src = Kb + (size_t)t * 64 * 128;
#pragma unroll
    for (int ii = 0; ii < 2; ii++) {
      int i = w * 2 + ii;                  // 0..15
      int row = i * 4 + (l >> 4);          // 0..63 key-in-tile
      int ck = (l & 15) ^ (row & 15);      // inverse swizzle on source
      async16(src + row * 128 + ck * 8, Kl + i * 1024 + l * 16);
    }
  };
  auto stageV = [&](int buf, int t) {
    char* Vl = smem + 32768 + buf * 16384;
    const bfu* src = Vb + t * 64;
#pragma unroll
    for (int jj = 0; jj < 2; jj++) {
      int j = w * 2 + jj;                  // 0..15
      int row = j * 8 + (l >> 3);          // 0..127 d
      int ck = (l & 7) ^ (row & 7);
      async16(src + (size_t)row * 2048 + ck * 8, Vl + j * 1024 + l * 16);
    }
  };

  bf16x8 qf[8];
#pragma unroll
  for (int dt = 0; dt < 8; dt++)
    qf[dt] = *(const bf16x8*)(Qh + (size_t)myrow * 128 + dt * 16 + h2 * 8);

  f32x16 O[4];  // O^T tiles over d (4 x 32)
#pragma unroll
  for (int mt = 0; mt < 4; mt++)
#pragma unroll
    for (int r = 0; r < 16; r++) O[mt][r] = 0.f;
  float li = 0.f;

  stageK(0, 0);
  stageV(0, 0);

#pragma unroll 1
  for (int t = 0; t < NT; t++) {
    // top barrier: K(t),V(t) resident (own 4 loads one full step old ->
    // vmcnt(0) ~free); all waves past their step t-1 reads -> safe to stage.
    wait0_bar();
    if (t + 1 < NT) {
      stageK((t + 1) & 1, t + 1);
      stageV((t + 1) & 1, t + 1);
    }

    const int k0 = t * 64;
    if (k0 <= qrow0 + 31) {
      const char* Kl = smem + (t & 1) * 16384;
      const char* Vl = smem + 32768 + (t & 1) * 16384;

      f32x16 S0, S1;  // S^T: m=key(32), n=row(32)
#pragma unroll
      for (int r = 0; r < 16; r++) { S0[r] = 0.f; S1[r] = 0.f; }
      const int swk = (ln & 15) << 4;
      __builtin_amdgcn_s_setprio(1);
#pragma unroll
      for (int dt = 0; dt < 8; dt++) {
        bf16x8 kf0 =
            *(const bf16x8*)(Kl + ln * 256 + ((dt * 32 + h2 * 16) ^ swk));
        bf16x8 kf1 = *(const bf16x8*)(Kl + (32 + ln) * 256 +
                                      ((dt * 32 + h2 * 16) ^ swk));
        S0 = __builtin_amdgcn_mfma_f32_32x32x16_bf16(kf0, qf[dt], S0, 0, 0, 0);
        S1 = __builtin_amdgcn_mfma_f32_32x32x16_bf16(kf1, qf[dt], S1, 0, 0, 0);
      }
      __builtin_amdgcn_s_setprio(0);

      const bool need_mask = (k0 + 63) > qrow0;
      bf16x8 pfr[4];
#pragma unroll
      for (int half = 0; half < 2; half++) {
        float p[16];
#pragma unroll
        for (int r = 0; r < 16; r++) {
          float s = half ? S1[r] : S0[r];
          float pv = __builtin_exp2f(fmaf(s, 0.12751743f, -17.312340f));
          if (need_mask) {
            int key = k0 + half * 32 + (r & 3) + 8 * (r >> 2) + 4 * h2;
            if (key > myrow) pv = 0.f;
          }
          p[r] = pv;
          li += pv;
        }
#pragma unroll
        for (int kt = 0; kt < 2; kt++) {
          const float* q = p + kt * 8;
          unsigned int a0 = cvtpk(q[0], q[1]);
          unsigned int a1 = cvtpk(q[2], q[3]);
          unsigned int b0 = cvtpk(q[4], q[5]);
          unsigned int b1 = cvtpk(q[6], q[7]);
          pl32swap(a0, b0);
          pl32swap(a1, b1);
          union { unsigned int u[4]; bf16x8 v; } c;
          c.u[0] = a0; c.u[1] = a1; c.u[2] = b0; c.u[3] = b1;
          pfr[half * 2 + kt] = c.v;
        }
      }

      const int swv = (ln & 7) << 4;
      __builtin_amdgcn_s_setprio(1);
#pragma unroll
      for (int mt = 0; mt < 4; mt++) {
        const char* vb = Vl + (mt * 32 + ln) * 128;
#pragma unroll
        for (int kt = 0; kt < 4; kt++) {
          bf16x8 vf = *(const bf16x8*)(vb + ((kt * 32 + h2 * 16) ^ swv));
          O[mt] = __builtin_amdgcn_mfma_f32_32x32x16_bf16(vf, pfr[kt], O[mt], 0, 0, 0);
        }
      }
      __builtin_amdgcn_s_setprio(0);
    }
  }

  // epilogue: row sum over lane halves, scale, pack, store
  li += __shfl_xor(li, 32);
  const float inv = 1.f / li;
  bfu* orow = attn + ((size_t)(b * 2048 + qrow0 + ln)) * 2048 + hh * 128;
#pragma unroll
  for (int mt = 0; mt < 4; mt++)
#pragma unroll
    for (int g = 0; g < 4; g++) {
      unsigned int r0 = cvtpk(O[mt][g * 4 + 0] * inv, O[mt][g * 4 + 1] * inv);
      unsigned int r1 = cvtpk(O[mt][g * 4 + 2] * inv, O[mt][g * 4 + 3] * inv);
      uint2 o; o.x = r0; o.y = r1;
      *(uint2*)(orow + mt * 32 + g * 8 + h2 * 4) = o;
    }
}

// ---------------- launch ----------------
extern "C" void kernel_launch(void* const* d_in, const int* in_sizes, int n_in,
                              void* d_out, int out_size, void* d_ws, size_t ws_size,
                              hipStream_t stream) {
  const float* x = (const float*)d_in[0];
  const float* Wq = (const float*)d_in[1];
  const float* Wk = (const float*)d_in[2];
  const float* Wv = (const float*)d_in[3];
  const float* Wo = (const float*)d_in[4];
  float* out = (float*)d_out;
  char* ws = (char*)d_ws;

  // workspace layout (bytes)
  bfu* xb     = (bfu*)(ws);               // 33,554,432  [8192 x 2048]
  bfu* Wqkv   = (bfu*)(ws + 33554432);    // 16,777,216  [4096 x 2048]
  bfu* Wob    = (bfu*)(ws + 50331648);    //  8,388,608  [2048 x 2048]
  float2* tab = (float2*)(ws + 58720256); //  1,048,576  [2048 x 64] cos/sin
  bfu* qT     = (bfu*)(ws + 125829120);   // 33,554,432  [B,16,T,128]
  bfu* kT     = (bfu*)(ws + 159383552);   // 16,777,216  [B,8,T,128]
  bfu* vT     = (bfu*)(ws + 176160768);   // 16,777,216  [B,8,128,T]
  bfu* attn = xb;                          // reuse xb region (alias-safe)

  cvt_bf16<<<16384, 256, 0, stream>>>(x, xb, 4194304);
  cvt_weights<<<12288, 256, 0, stream>>>(Wq, Wk, Wv, Wo, Wqkv, Wob);
  rope_table<<<512, 256, 0, stream>>>(tab);

  // fused QKV GEMM: writes qT/kT (RoPE'd) and vT (transposed) directly
  gemm256<bfu, true><<<dim3(32, 16), 512, 0, stream>>>(
      xb, Wqkv, (bfu*)nullptr, tab, qT, kT, vT, 8192, 4096, 2048);
  flash_attn8<<<512, 512, 0, stream>>>(qT, kT, vT, attn);
  gemm128<<<dim3(64, 16), 512, 0, stream>>>(attn, Wob, out, 8192, 2048, 2048);
}